// Round 1
// baseline (837.744 us; speedup 1.0000x reference)
//
#include <hip/hip_runtime.h>
#include <cmath>

#define B 64
#define S 80
#define KC 32
#define EDIM 256
#define HDIM 512
#define G3 1536
#define LDIM 128

// ---------------------------------------------------------------------------
// K1: multi-hot embedding + tanh.  emb[b*S+s][e] = tanh(sum over unique
// nonzero codes c of Ew[c][e]).  One block per (b,s), 256 threads = EDIM.
__global__ __launch_bounds__(256) void emb_kernel(const int* __restrict__ seq,
                                                  const float* __restrict__ Ew,
                                                  float* __restrict__ emb) {
    int bs = blockIdx.x;
    __shared__ int codes[KC];
    __shared__ int valid[KC];
    int tid = threadIdx.x;
    if (tid < KC) codes[tid] = seq[bs * KC + tid];
    __syncthreads();
    if (tid < KC) {
        int c = codes[tid];
        int v = (c != 0);
        for (int i = 0; i < tid; ++i)
            if (codes[i] == c) v = 0;   // keep first occurrence only
        valid[tid] = v;
    }
    __syncthreads();
    float acc = 0.f;
    for (int j = 0; j < KC; ++j) {
        if (valid[j]) acc += Ew[codes[j] * EDIM + tid];
    }
    emb[bs * EDIM + tid] = tanhf(acc);
}

// ---------------------------------------------------------------------------
// K2: Gi = emb @ Wi^T + bi.  M=B*S=5120, N=3H=1536, K=E=256.
// Both operands row-major with K contiguous (NT gemm). 64x64 tile, 4x4/thread.
__global__ __launch_bounds__(256) void gi_gemm(const float* __restrict__ A,
                                               const float* __restrict__ Bw,
                                               const float* __restrict__ bi,
                                               float* __restrict__ C) {
    __shared__ float As[32][68];
    __shared__ float Bs[32][68];
    int m0 = blockIdx.x * 64;
    int n0 = blockIdx.y * 64;
    int tid = threadIdx.x;
    int tm = tid & 15, tn = tid >> 4;
    float acc[4][4] = {};
    for (int k0 = 0; k0 < EDIM; k0 += 32) {
        #pragma unroll
        for (int i = 0; i < 8; ++i) {
            int idx = tid + i * 256;       // 0..2047
            int kk = idx & 31, mm = idx >> 5;
            As[kk][mm] = A[(m0 + mm) * EDIM + k0 + kk];
            Bs[kk][mm] = Bw[(n0 + mm) * EDIM + k0 + kk];
        }
        __syncthreads();
        #pragma unroll
        for (int kk = 0; kk < 32; ++kk) {
            float a[4], bb[4];
            #pragma unroll
            for (int i = 0; i < 4; ++i) a[i] = As[kk][tm * 4 + i];
            #pragma unroll
            for (int j = 0; j < 4; ++j) bb[j] = Bs[kk][tn * 4 + j];
            #pragma unroll
            for (int i = 0; i < 4; ++i)
                #pragma unroll
                for (int j = 0; j < 4; ++j) acc[i][j] += a[i] * bb[j];
        }
        __syncthreads();
    }
    #pragma unroll
    for (int i = 0; i < 4; ++i)
        #pragma unroll
        for (int j = 0; j < 4; ++j) {
            int m = m0 + tm * 4 + i, n = n0 + tn * 4 + j;
            C[(size_t)m * G3 + n] = acc[i][j] + bi[n];
        }
}

// ---------------------------------------------------------------------------
// K3: rank[b] = position of patient b in stable argsort(-length).
__global__ void rank_kernel(const int* __restrict__ len, int* __restrict__ rank) {
    int b = threadIdx.x;
    if (b < B) {
        int lb = len[b];
        int r = 0;
        for (int i = 0; i < B; ++i) {
            int li = len[i];
            r += (li > lb) || (li == lb && i < b);
        }
        rank[b] = r;
    }
}

__global__ void hzero_kernel(float* __restrict__ h) {
    h[blockIdx.x * 256 + threadIdx.x] = 0.f;
}

// ---------------------------------------------------------------------------
// K4: one GRU step.  Block = (8 gate columns) x (16 patients); computes the
// r/z/n rows for its j-slice over all K=512, applies gates, writes hout.
// Double-buffered h to avoid intra-step read/write races between blocks.
__global__ __launch_bounds__(256) void gru_step(const float* __restrict__ Gi,
                                                const float* __restrict__ Wh,
                                                const float* __restrict__ bh,
                                                const int* __restrict__ len,
                                                const float* __restrict__ hin,
                                                float* __restrict__ hout,
                                                int t) {
    __shared__ float hs[16][HDIM + 4];
    __shared__ float red[128][3];
    int j0 = blockIdx.x * 8;
    int b0 = blockIdx.y * 16;
    int tid = threadIdx.x;
    // stage 16x512 h tile (float4, padded rows: 2064B -> 16B aligned)
    #pragma unroll
    for (int i = 0; i < 8; ++i) {
        int f4 = tid + i * 256;        // 0..2047
        int b  = f4 >> 7;
        int kq = f4 & 127;
        float4 v = *(const float4*)(hin + (size_t)(b0 + b) * HDIM + kq * 4);
        *(float4*)&hs[b][kq * 4] = v;
    }
    __syncthreads();

    int pair  = tid & 127;
    int khalf = tid >> 7;              // split-K over 2 halves of 256
    int b = pair & 15;
    int j = pair >> 4;
    int jr = j0 + j, jz = HDIM + jr, jn = 2 * HDIM + jr;
    const float4* wr4 = (const float4*)(Wh + (size_t)jr * HDIM);
    const float4* wz4 = (const float4*)(Wh + (size_t)jz * HDIM);
    const float4* wn4 = (const float4*)(Wh + (size_t)jn * HDIM);
    int kq0 = khalf * 64;
    float accr = 0.f, accz = 0.f, accn = 0.f;
    #pragma unroll 4
    for (int kq = 0; kq < 64; ++kq) {
        float4 hv = *(const float4*)&hs[b][(kq0 + kq) * 4];
        float4 a = wr4[kq0 + kq];
        float4 c = wz4[kq0 + kq];
        float4 d = wn4[kq0 + kq];
        accr += a.x * hv.x + a.y * hv.y + a.z * hv.z + a.w * hv.w;
        accz += c.x * hv.x + c.y * hv.y + c.z * hv.z + c.w * hv.w;
        accn += d.x * hv.x + d.y * hv.y + d.z * hv.z + d.w * hv.w;
    }
    if (khalf) { red[pair][0] = accr; red[pair][1] = accz; red[pair][2] = accn; }
    __syncthreads();
    if (!khalf) {
        accr += red[pair][0]; accz += red[pair][1]; accn += red[pair][2];
        int bg = b0 + b;
        const float* gi = Gi + ((size_t)bg * S + t) * G3;
        float r  = 1.f / (1.f + expf(-(gi[jr] + accr + bh[jr])));
        float z  = 1.f / (1.f + expf(-(gi[jz] + accz + bh[jz])));
        float nn = tanhf(gi[jn] + r * (accn + bh[jn]));
        float hold = hs[b][jr];
        float hnew = (t < len[bg]) ? ((1.f - z) * nn + z * hold) : hold;
        hout[(size_t)bg * HDIM + jr] = hnew;
    }
}

// ---------------------------------------------------------------------------
// K5: out[rank[b]] = tanh(W_lat @ h[b] + b_lat)
__global__ __launch_bounds__(128) void final_kernel(const float* __restrict__ h,
                                                    const float* __restrict__ Wl,
                                                    const float* __restrict__ bl,
                                                    const int* __restrict__ rank,
                                                    float* __restrict__ out) {
    int b = blockIdx.x;
    int l = threadIdx.x;
    __shared__ float hsh[HDIM];
    for (int i = l; i < HDIM; i += LDIM) hsh[i] = h[(size_t)b * HDIM + i];
    __syncthreads();
    float acc = bl[l];
    for (int k = 0; k < HDIM; ++k) acc += hsh[k] * Wl[(size_t)l * HDIM + k];
    out[(size_t)rank[b] * LDIM + l] = tanhf(acc);
}

// ---------------------------------------------------------------------------
extern "C" void kernel_launch(void* const* d_in, const int* in_sizes, int n_in,
                              void* d_out, int out_size, void* d_ws, size_t ws_size,
                              hipStream_t stream) {
    const int*   seq = (const int*)d_in[0];
    const int*   len = (const int*)d_in[1];
    const float* Ew  = (const float*)d_in[2];
    const float* Wi  = (const float*)d_in[3];
    const float* Wh  = (const float*)d_in[4];
    const float* bi  = (const float*)d_in[5];
    const float* bh  = (const float*)d_in[6];
    const float* Wl  = (const float*)d_in[7];
    const float* bl  = (const float*)d_in[8];
    float* out = (float*)d_out;

    float* ws  = (float*)d_ws;
    float* emb = ws;                               // B*S*E      = 1,310,720 f
    float* Gi  = emb + (size_t)B * S * EDIM;       // B*S*3H     = 7,864,320 f
    float* h0  = Gi + (size_t)B * S * G3;          // B*H        = 32,768 f
    float* h1  = h0 + (size_t)B * HDIM;            // B*H
    int*   rank = (int*)(h1 + (size_t)B * HDIM);   // B ints

    emb_kernel<<<B * S, 256, 0, stream>>>(seq, Ew, emb);
    dim3 g2(B * S / 64, G3 / 64);
    gi_gemm<<<g2, 256, 0, stream>>>(emb, Wi, bi, Gi);
    rank_kernel<<<1, 64, 0, stream>>>(len, rank);
    hzero_kernel<<<(B * HDIM) / 256, 256, 0, stream>>>(h0);

    float* hb[2] = { h0, h1 };
    for (int t = 0; t < S; ++t) {
        gru_step<<<dim3(HDIM / 8, B / 16), 256, 0, stream>>>(
            Gi, Wh, bh, len, hb[t & 1], hb[(t + 1) & 1], t);
    }
    // after t = S-1, result lives in hb[S & 1] == h0 (S = 80 even)
    final_kernel<<<B, LDIM, 0, stream>>>(h0, Wl, bl, rank, out);
}